// Round 1
// baseline (1085.869 us; speedup 1.0000x reference)
//
#include <hip/hip_runtime.h>

typedef __bf16 bf16_t;
typedef bf16_t bf16x4_t __attribute__((ext_vector_type(4)));
typedef bf16_t bf16x8_t __attribute__((ext_vector_type(8)));
typedef float  f32x4_t  __attribute__((ext_vector_type(4)));

#define RCHUNK 4096

// ---------------------------------------------------------------------------
// Weight packing: W[t][k][n] (f32) -> bf16, MFMA-B-fragment order.
// pack[((t*KB+kb)*NB+nb)*512 + l*8 + j] = W[t][kb*32 + (l>>4)*8 + j][nb*16 + (l&15)]
// so each lane reads its 16B fragment slice contiguously (ds/global b128).
// ---------------------------------------------------------------------------
__global__ void pack_w_kernel(const float* __restrict__ W, bf16_t* __restrict__ out,
                              int T, int K, int N)
{
  int KB = K >> 5, NB = N >> 4;
  int total = T * KB * NB * 512;
  for (int idx = blockIdx.x * blockDim.x + threadIdx.x; idx < total;
       idx += gridDim.x * blockDim.x) {
    int j  = idx & 7;
    int l  = (idx >> 3) & 63;
    int nb = (idx >> 9) % NB;
    int r  = idx / (512 * NB);
    int kb = r % KB;
    int t  = r / KB;
    int k = kb * 32 + ((l >> 4) << 3) + j;
    int n = nb * 16 + (l & 15);
    out[idx] = (bf16_t)W[((size_t)t * K + k) * N + n];
  }
}

// ---------------------------------------------------------------------------
// Stable counting-sort rank/perm over a small type alphabet T.
// rank[i] = sorted position of i (stable); perm[rank[i]] = i.
// ---------------------------------------------------------------------------
template <int T>
__global__ void count_types_kernel(const int* __restrict__ tv, int n,
                                   int* __restrict__ blkcnt)
{
  __shared__ int cnt[T];
  int tid = threadIdx.x, b = blockIdx.x;
  if (tid < T) cnt[tid] = 0;
  __syncthreads();
  int lo = b * RCHUNK, hi = min(n, lo + RCHUNK);
  int loc[T];
#pragma unroll
  for (int t = 0; t < T; ++t) loc[t] = 0;
  for (int i = lo + tid; i < hi; i += 256) {
    int tq = tv[i];
#pragma unroll
    for (int t = 0; t < T; ++t) loc[t] += (tq == t);   // compile-time index (no scratch)
  }
#pragma unroll
  for (int t = 0; t < T; ++t)
    if (loc[t]) atomicAdd(&cnt[t], loc[t]);
  __syncthreads();
  if (tid < T) blkcnt[b * T + tid] = cnt[tid];
}

// single block; requires nblocks <= 256 (196 for edges, 13 for nodes)
template <int T>
__global__ void scan_blocks_kernel(const int* __restrict__ blkcnt, int nblocks,
                                   int* __restrict__ blkbase)
{
  __shared__ int sh[256];
  __shared__ int tot[T];
  int tid = threadIdx.x;
  int myc[T], excl[T];
#pragma unroll
  for (int t = 0; t < T; ++t) myc[t] = (tid < nblocks) ? blkcnt[tid * T + t] : 0;
#pragma unroll
  for (int t = 0; t < T; ++t) {
    sh[tid] = myc[t];
    __syncthreads();
    for (int off = 1; off < 256; off <<= 1) {
      int v = (tid >= off) ? sh[tid - off] : 0;
      __syncthreads();
      sh[tid] += v;
      __syncthreads();
    }
    excl[t] = sh[tid] - myc[t];
    if (tid == 255) tot[t] = sh[255];
    __syncthreads();
  }
  if (tid < nblocks) {
    int run = 0;
#pragma unroll
    for (int t = 0; t < T; ++t) {
      blkbase[tid * T + t] = run + excl[t];
      run += tot[t];
    }
  }
}

template <int T>
__global__ void write_ranks_kernel(const int* __restrict__ tv, int n,
                                   const int* __restrict__ blkbase,
                                   int* __restrict__ rank, int* __restrict__ perm)
{
  __shared__ int sh[256];
  int tid = threadIdx.x, b = blockIdx.x;
  int lo = b * RCHUNK + tid * 16;
  int tvq[16];
  int myc[T];
#pragma unroll
  for (int t = 0; t < T; ++t) myc[t] = 0;
#pragma unroll
  for (int q = 0; q < 16; ++q) {
    int i = lo + q;
    int tq = (i < n) ? tv[i] : -1;
    tvq[q] = tq;
#pragma unroll
    for (int t = 0; t < T; ++t) myc[t] += (tq == t);
  }
  int mybase[T];
#pragma unroll
  for (int t = 0; t < T; ++t) {
    sh[tid] = myc[t];
    __syncthreads();
    for (int off = 1; off < 256; off <<= 1) {
      int v = (tid >= off) ? sh[tid - off] : 0;
      __syncthreads();
      sh[tid] += v;
      __syncthreads();
    }
    mybase[t] = blkbase[b * T + t] + sh[tid] - myc[t];
    __syncthreads();
  }
#pragma unroll
  for (int q = 0; q < 16; ++q) {
    int tq = tvq[q];
    if (tq < 0) continue;
    int r = 0;
#pragma unroll
    for (int t = 0; t < T; ++t)
      if (tq == t) { r = mybase[t]; mybase[t] = r + 1; }
    rank[lo + q] = r;
    perm[r] = lo + q;
  }
}

// ---------------------------------------------------------------------------
// Fused per-type 2-layer MLP over 64-row tiles in type-sorted order.
//   EDGE: x = [ef[e] | nf[src[e]] | nf[dst[e]]]  (K1=384), out -> new_ef[j],
//         atomicAdd into agg[dst[j]]  (j = rank[pos], pos = sorted position)
//   NODE: x = [agg[n] | nf[n]]                   (K1=256), out -> new_nf[j]
// 4 waves; wave w owns rows 32*(w&1)..+32, cols 64*(w>>1)..+64 (2x4 16x16 frags).
// LDS XOR-swizzle byte^((row&7)<<4) on all row-major tiles (G4/T2).
// ---------------------------------------------------------------------------
template <int K1, bool EDGE>
__global__ __launch_bounds__(256) void mlp_kernel(
    const float* __restrict__ nf, const float* __restrict__ feat,
    const int* __restrict__ src, const int* __restrict__ dst,
    const int* __restrict__ tvec,
    const int* __restrict__ perm, const int* __restrict__ rank,
    const bf16_t* __restrict__ pW1, const float* __restrict__ b1,
    const bf16_t* __restrict__ pW2, const float* __restrict__ b2,
    float* __restrict__ out, float* __restrict__ agg_out, int Ntot)
{
  constexpr int KB1 = K1 / 32;
  constexpr int K1B = K1 * 2;            // A-tile row bytes
  __shared__ char Asm[64 * K1B];         // x tile, bf16, swizzled
  __shared__ char Hsm[64 * 256];         // hidden tile, bf16, swizzled
  __shared__ char Bsm[8192];             // one K-step of B fragments
  __shared__ int sm_e[64], sm_j[64], sm_ty[64], sm_s0[64], sm_s1[64], sm_dj[64];
  __shared__ int sm_tmin, sm_tmax;

  const int tid = threadIdx.x;
  const int l = tid & 63, w = tid >> 6;
  const int base = blockIdx.x * 64;

  if (tid < 64) {
    int pos = base + tid;
    if (pos < Ntot) {
      int e = perm[pos];
      int j = rank[pos];
      sm_e[tid] = e;
      sm_j[tid] = j;
      sm_ty[tid] = tvec[e];
      if (EDGE) {
        sm_s0[tid] = src[e];
        sm_s1[tid] = dst[e];
        sm_dj[tid] = dst[j];      // aggregation target is dst at FINAL index
      }
    } else {
      sm_e[tid] = 0; sm_j[tid] = -1; sm_ty[tid] = -1;
      if (EDGE) { sm_s0[tid] = 0; sm_s1[tid] = 0; sm_dj[tid] = 0; }
    }
  }
  __syncthreads();
  if (tid == 0) {
    int a = 1 << 30, bm = -1;
    for (int r = 0; r < 64; ++r) {
      int t = sm_ty[r];
      if (t >= 0) { a = t < a ? t : a; bm = t > bm ? t : bm; }
    }
    sm_tmin = a; sm_tmax = bm;
  }
  __syncthreads();

  // ---- stage x -> Asm (f32 -> bf16, swizzled) ----
  constexpr int C4 = K1 / 4;             // float4 chunks per row
  for (int c = tid; c < 64 * C4; c += 256) {
    int row = c / C4, q = c - row * C4;
    int seg = q >> 5, col4 = q & 31;
    f32x4_t v = {0.f, 0.f, 0.f, 0.f};
    if (sm_j[row] >= 0) {
      const float* p;
      if (EDGE) {
        p = (seg == 0) ? feat + (size_t)sm_e[row] * 128
          : (seg == 1) ? nf + (size_t)sm_s0[row] * 128
                       : nf + (size_t)sm_s1[row] * 128;
      } else {
        p = (seg == 0) ? feat + (size_t)sm_e[row] * 128
                       : nf + (size_t)sm_e[row] * 128;
      }
      v = *(const f32x4_t*)(p + (col4 << 2));
    }
    bf16x4_t bv;
    bv[0] = (bf16_t)v[0]; bv[1] = (bf16_t)v[1];
    bv[2] = (bf16_t)v[2]; bv[3] = (bf16_t)v[3];
    int byteoff = seg * 256 + col4 * 8;
    *(bf16x4_t*)(Asm + row * K1B + (byteoff ^ ((row & 7) << 4))) = bv;
  }

  const int rb = (w & 1) * 32;
  const int cb = (w >> 1) * 64;
  const int kgrp = (l >> 4) << 4;        // lane's 16B offset within a K-step

  for (int t = sm_tmin; t <= sm_tmax; ++t) {
    f32x4_t acc[2][4];
#pragma unroll
    for (int m = 0; m < 2; ++m)
#pragma unroll
      for (int n = 0; n < 4; ++n) acc[m][n] = (f32x4_t){0.f, 0.f, 0.f, 0.f};

    // ---------- layer 1: [64,K1] @ [K1,128] ----------
    for (int kb = 0; kb < KB1; ++kb) {
      __syncthreads();
      {
        const uint4* g = (const uint4*)(pW1 + ((size_t)(t * KB1 + kb)) * 4096);
        uint4* d4 = (uint4*)Bsm;
        d4[tid] = g[tid];
        d4[tid + 256] = g[tid + 256];
      }
      __syncthreads();
      bf16x8_t afr[2], bfr[4];
#pragma unroll
      for (int m = 0; m < 2; ++m) {
        int row = rb + 16 * m + (l & 15);
        int kbyte = kb * 64 + kgrp;
        afr[m] = *(const bf16x8_t*)(Asm + row * K1B + (kbyte ^ ((row & 7) << 4)));
      }
#pragma unroll
      for (int n = 0; n < 4; ++n) {
        int nfr = (cb >> 4) + n;
        bfr[n] = *(const bf16x8_t*)(Bsm + ((nfr << 6) + l) * 16);
      }
#pragma unroll
      for (int m = 0; m < 2; ++m)
#pragma unroll
        for (int n = 0; n < 4; ++n)
          acc[m][n] = __builtin_amdgcn_mfma_f32_16x16x32_bf16(afr[m], bfr[n],
                                                              acc[m][n], 0, 0, 0);
    }

    // bias + relu -> Hsm (bf16, swizzled). C/D layout: col=l&15, row=(l>>4)*4+jj.
#pragma unroll
    for (int n = 0; n < 4; ++n) {
      int col = cb + 16 * n + (l & 15);
      float bh = b1[t * 128 + col];
#pragma unroll
      for (int m = 0; m < 2; ++m)
#pragma unroll
        for (int jj = 0; jj < 4; ++jj) {
          int row = rb + 16 * m + ((l >> 4) << 2) + jj;
          float v = acc[m][n][jj] + bh;
          v = v > 0.f ? v : 0.f;
          *(bf16_t*)(Hsm + row * 256 + ((col * 2) ^ ((row & 7) << 4))) = (bf16_t)v;
        }
    }

#pragma unroll
    for (int m = 0; m < 2; ++m)
#pragma unroll
      for (int n = 0; n < 4; ++n) acc[m][n] = (f32x4_t){0.f, 0.f, 0.f, 0.f};

    // ---------- layer 2: [64,128] @ [128,128] ----------
    for (int kb = 0; kb < 4; ++kb) {
      __syncthreads();   // also guarantees Hsm writes visible before first read
      {
        const uint4* g = (const uint4*)(pW2 + ((size_t)(t * 4 + kb)) * 4096);
        uint4* d4 = (uint4*)Bsm;
        d4[tid] = g[tid];
        d4[tid + 256] = g[tid + 256];
      }
      __syncthreads();
      bf16x8_t afr[2], bfr[4];
#pragma unroll
      for (int m = 0; m < 2; ++m) {
        int row = rb + 16 * m + (l & 15);
        int kbyte = kb * 64 + kgrp;
        afr[m] = *(const bf16x8_t*)(Hsm + row * 256 + (kbyte ^ ((row & 7) << 4)));
      }
#pragma unroll
      for (int n = 0; n < 4; ++n) {
        int nfr = (cb >> 4) + n;
        bfr[n] = *(const bf16x8_t*)(Bsm + ((nfr << 6) + l) * 16);
      }
#pragma unroll
      for (int m = 0; m < 2; ++m)
#pragma unroll
        for (int n = 0; n < 4; ++n)
          acc[m][n] = __builtin_amdgcn_mfma_f32_16x16x32_bf16(afr[m], bfr[n],
                                                              acc[m][n], 0, 0, 0);
    }

    // ---------- epilogue: bias, scatter to out[j], atomic agg ----------
#pragma unroll
    for (int n = 0; n < 4; ++n) {
      int col = cb + 16 * n + (l & 15);
      float bo = b2[t * 128 + col];
#pragma unroll
      for (int m = 0; m < 2; ++m)
#pragma unroll
        for (int jj = 0; jj < 4; ++jj) {
          int row = rb + 16 * m + ((l >> 4) << 2) + jj;
          if (sm_j[row] >= 0 && sm_ty[row] == t) {
            float v = acc[m][n][jj] + bo;
            out[(size_t)sm_j[row] * 128 + col] = v;
            if (EDGE)
              unsafeAtomicAdd(agg_out + (size_t)sm_dj[row] * 128 + col, v);
          }
        }
    }
  }
}

// ---------------------------------------------------------------------------
extern "C" void kernel_launch(void* const* d_in, const int* in_sizes, int n_in,
                              void* d_out, int out_size, void* d_ws, size_t ws_size,
                              hipStream_t stream)
{
  const float* nf    = (const float*)d_in[0];
  const float* ef    = (const float*)d_in[1];
  const int*   src   = (const int*)d_in[2];
  const int*   dst   = (const int*)d_in[3];
  const int*   etype = (const int*)d_in[4];
  const int*   ntype = (const int*)d_in[5];
  const float* Weh   = (const float*)d_in[6];
  const float* beh   = (const float*)d_in[7];
  const float* Weo   = (const float*)d_in[8];
  const float* beo   = (const float*)d_in[9];
  const float* Wnh   = (const float*)d_in[10];
  const float* bnh   = (const float*)d_in[11];
  const float* Wno   = (const float*)d_in[12];
  const float* bno   = (const float*)d_in[13];

  const int E = in_sizes[2];   // 800000
  const int N = in_sizes[5];   // 50000
  const int TE = 3, TN = 2;

  char* ws = (char*)d_ws;
  size_t off = 0;
  auto alloc = [&](size_t bytes) -> char* {
    char* p = ws + off;
    off = (off + bytes + 511) & ~(size_t)511;
    return p;
  };
  bf16_t* pWeh = (bf16_t*)alloc((size_t)TE * 12 * 8 * 512 * 2);
  bf16_t* pWeo = (bf16_t*)alloc((size_t)TE * 4 * 8 * 512 * 2);
  bf16_t* pWnh = (bf16_t*)alloc((size_t)TN * 8 * 8 * 512 * 2);
  bf16_t* pWno = (bf16_t*)alloc((size_t)TN * 4 * 8 * 512 * 2);
  int* rank_e = (int*)alloc((size_t)E * 4);
  int* perm_e = (int*)alloc((size_t)E * 4);
  int* rank_n = (int*)alloc((size_t)N * 4);
  int* perm_n = (int*)alloc((size_t)N * 4);
  const int NBE = (E + RCHUNK - 1) / RCHUNK;   // 196 (<=256 for scan kernel)
  const int NBN = (N + RCHUNK - 1) / RCHUNK;   // 13
  int* blkcnt_e  = (int*)alloc((size_t)NBE * TE * 4);
  int* blkbase_e = (int*)alloc((size_t)NBE * TE * 4);
  int* blkcnt_n  = (int*)alloc((size_t)NBN * TN * 4);
  int* blkbase_n = (int*)alloc((size_t)NBN * TN * 4);
  float* agg = (float*)alloc((size_t)N * 128 * 4);
  (void)ws_size; (void)n_in; (void)out_size;

  hipMemsetAsync(agg, 0, (size_t)N * 128 * 4, stream);

  pack_w_kernel<<<288, 256, 0, stream>>>(Weh, pWeh, TE, 384, 128);
  pack_w_kernel<<<96, 256, 0, stream>>>(Weo, pWeo, TE, 128, 128);
  pack_w_kernel<<<128, 256, 0, stream>>>(Wnh, pWnh, TN, 256, 128);
  pack_w_kernel<<<64, 256, 0, stream>>>(Wno, pWno, TN, 128, 128);

  count_types_kernel<3><<<NBE, 256, 0, stream>>>(etype, E, blkcnt_e);
  scan_blocks_kernel<3><<<1, 256, 0, stream>>>(blkcnt_e, NBE, blkbase_e);
  write_ranks_kernel<3><<<NBE, 256, 0, stream>>>(etype, E, blkbase_e, rank_e, perm_e);

  count_types_kernel<2><<<NBN, 256, 0, stream>>>(ntype, N, blkcnt_n);
  scan_blocks_kernel<2><<<1, 256, 0, stream>>>(blkcnt_n, NBN, blkbase_n);
  write_ranks_kernel<2><<<NBN, 256, 0, stream>>>(ntype, N, blkbase_n, rank_n, perm_n);

  float* out_nf = (float*)d_out;                      // new_nf first (return order)
  float* out_ef = (float*)d_out + (size_t)N * 128;    // then new_ef

  mlp_kernel<384, true><<<(E + 63) / 64, 256, 0, stream>>>(
      nf, ef, src, dst, etype, perm_e, rank_e,
      pWeh, beh, pWeo, beo, out_ef, agg, E);

  mlp_kernel<256, false><<<(N + 63) / 64, 256, 0, stream>>>(
      nf, agg, nullptr, nullptr, ntype, perm_n, rank_n,
      pWnh, bnh, pWno, bno, out_nf, nullptr, N);
}

// Round 2
// 987.664 us; speedup vs baseline: 1.0994x; 1.0994x over previous
//
#include <hip/hip_runtime.h>

typedef __bf16 bf16_t;
typedef bf16_t bf16x8_t __attribute__((ext_vector_type(8)));
typedef float  f32x4_t  __attribute__((ext_vector_type(4)));

#define RCHUNK 4096
#define SELP(kbv, a, b, c) (((kbv) < 4) ? (a) : (((kbv) < 8) ? (b) : (c)))

// ---------------------------------------------------------------------------
// Weight packing: W[t][k][n] (f32) -> bf16, MFMA-B-fragment order.
// pack[((t*KB+kb)*NB+nb)*512 + l*8 + j] = W[t][kb*32 + (l>>4)*8 + j][nb*16 + (l&15)]
// ---------------------------------------------------------------------------
__global__ void pack_w_kernel(const float* __restrict__ W, bf16_t* __restrict__ out,
                              int T, int K, int N)
{
  int KB = K >> 5, NB = N >> 4;
  int total = T * KB * NB * 512;
  for (int idx = blockIdx.x * blockDim.x + threadIdx.x; idx < total;
       idx += gridDim.x * blockDim.x) {
    int j  = idx & 7;
    int l  = (idx >> 3) & 63;
    int nb = (idx >> 9) % NB;
    int r  = idx / (512 * NB);
    int kb = r % KB;
    int t  = r / KB;
    int k = kb * 32 + ((l >> 4) << 3) + j;
    int n = nb * 16 + (l & 15);
    out[idx] = (bf16_t)W[((size_t)t * K + k) * N + n];
  }
}

// ---------------------------------------------------------------------------
// Stable counting-sort rank/perm over a small type alphabet T.
// ---------------------------------------------------------------------------
template <int T>
__global__ void count_types_kernel(const int* __restrict__ tv, int n,
                                   int* __restrict__ blkcnt)
{
  __shared__ int cnt[T];
  int tid = threadIdx.x, b = blockIdx.x;
  if (tid < T) cnt[tid] = 0;
  __syncthreads();
  int lo = b * RCHUNK, hi = min(n, lo + RCHUNK);
  int loc[T];
#pragma unroll
  for (int t = 0; t < T; ++t) loc[t] = 0;
  for (int i = lo + tid; i < hi; i += 256) {
    int tq = tv[i];
#pragma unroll
    for (int t = 0; t < T; ++t) loc[t] += (tq == t);
  }
#pragma unroll
  for (int t = 0; t < T; ++t)
    if (loc[t]) atomicAdd(&cnt[t], loc[t]);
  __syncthreads();
  if (tid < T) blkcnt[b * T + tid] = cnt[tid];
}

template <int T>
__global__ void scan_blocks_kernel(const int* __restrict__ blkcnt, int nblocks,
                                   int* __restrict__ blkbase)
{
  __shared__ int sh[256];
  __shared__ int tot[T];
  int tid = threadIdx.x;
  int myc[T], excl[T];
#pragma unroll
  for (int t = 0; t < T; ++t) myc[t] = (tid < nblocks) ? blkcnt[tid * T + t] : 0;
#pragma unroll
  for (int t = 0; t < T; ++t) {
    sh[tid] = myc[t];
    __syncthreads();
    for (int off = 1; off < 256; off <<= 1) {
      int v = (tid >= off) ? sh[tid - off] : 0;
      __syncthreads();
      sh[tid] += v;
      __syncthreads();
    }
    excl[t] = sh[tid] - myc[t];
    if (tid == 255) tot[t] = sh[255];
    __syncthreads();
  }
  if (tid < nblocks) {
    int run = 0;
#pragma unroll
    for (int t = 0; t < T; ++t) {
      blkbase[tid * T + t] = run + excl[t];
      run += tot[t];
    }
  }
}

template <int T>
__global__ void write_ranks_kernel(const int* __restrict__ tv, int n,
                                   const int* __restrict__ blkbase,
                                   int* __restrict__ rank, int* __restrict__ perm)
{
  __shared__ int sh[256];
  int tid = threadIdx.x, b = blockIdx.x;
  int lo = b * RCHUNK + tid * 16;
  int tvq[16];
  int myc[T];
#pragma unroll
  for (int t = 0; t < T; ++t) myc[t] = 0;
#pragma unroll
  for (int q = 0; q < 16; ++q) {
    int i = lo + q;
    int tq = (i < n) ? tv[i] : -1;
    tvq[q] = tq;
#pragma unroll
    for (int t = 0; t < T; ++t) myc[t] += (tq == t);
  }
  int mybase[T];
#pragma unroll
  for (int t = 0; t < T; ++t) {
    sh[tid] = myc[t];
    __syncthreads();
    for (int off = 1; off < 256; off <<= 1) {
      int v = (tid >= off) ? sh[tid - off] : 0;
      __syncthreads();
      sh[tid] += v;
      __syncthreads();
    }
    mybase[t] = blkbase[b * T + t] + sh[tid] - myc[t];
    __syncthreads();
  }
#pragma unroll
  for (int q = 0; q < 16; ++q) {
    int tq = tvq[q];
    if (tq < 0) continue;
    int r = 0;
#pragma unroll
    for (int t = 0; t < T; ++t)
      if (tq == t) { r = mybase[t]; mybase[t] = r + 1; }
    rank[lo + q] = r;
    perm[r] = lo + q;
  }
}

// ---------------------------------------------------------------------------
// Weight-stationary fused 2-layer MLP over 128-row tiles, type-sorted order.
// 512 threads / 8 waves; wave grid 4x2: wave owns rows 32*(w>>1)..+32,
// cols 64*(w&1)..+64 (2x4 frags of 16x16x32 MFMA).
// W1 (K1x128 bf16) LDS-resident per type; W2 (128x128) in registers
// (16 x bf16x8 per lane); A fragments loaded global->reg with f32->bf16 cvt
// (1-deep prefetch); hidden tile through swizzled LDS. No barriers in K-loops.
// ---------------------------------------------------------------------------
template <int K1, bool EDGE>
__global__ __launch_bounds__(512) void mlp2_kernel(
    const float* __restrict__ nf, const float* __restrict__ feat,
    const int* __restrict__ src, const int* __restrict__ dst,
    const int* __restrict__ tvec,
    const int* __restrict__ perm, const int* __restrict__ rank,
    const bf16_t* __restrict__ pW1, const float* __restrict__ b1,
    const bf16_t* __restrict__ pW2, const float* __restrict__ b2,
    float* __restrict__ out, float* __restrict__ agg_out, int Ntot)
{
  constexpr int KB1 = K1 / 32;
  __shared__ char Wsm[KB1 * 8192];     // W1, fragment order: (kb, nfr) 1KB chunks
  __shared__ char Hsm[128 * 256];      // hidden tile, bf16, XOR-swizzled
  __shared__ int sm_j[128], sm_ty[128], sm_e[128];
  __shared__ int sm_s0[128], sm_s1[128], sm_dj[128];
  __shared__ int sm_tmin, sm_tmax;

  const int tid = threadIdx.x;
  const int l = tid & 63, w = tid >> 6;
  const int wr = w >> 1, wc = w & 1;
  const int rb = wr * 32, cb = wc * 64;
  const int l15 = l & 15;
  const int koff = (l >> 4) << 3;      // float offset of lane's 8-float k-window

  const int tiles = (Ntot + 127) >> 7;
  const int tpb = (tiles + gridDim.x - 1) / gridDim.x;
  const int tb0 = blockIdx.x * tpb;
  const int tb1 = min(tiles, tb0 + tpb);

  int cur_t = -1;
  bf16x8_t w2r[16];                    // [kb*4+n], static-indexed under unroll
  float bh[4], bo[4];

  for (int tile = tb0; tile < tb1; ++tile) {
    const int base = tile << 7;
    __syncthreads();                   // protect meta/Hsm from prev-tile readers
    if (tid < 128) {
      int pos = base + tid;
      if (pos < Ntot) {
        int e = perm[pos], j = rank[pos];
        sm_e[tid] = e; sm_j[tid] = j; sm_ty[tid] = tvec[e];
        if (EDGE) { sm_s0[tid] = src[e]; sm_s1[tid] = dst[e]; sm_dj[tid] = dst[j]; }
      } else {
        sm_e[tid] = 0; sm_j[tid] = -1; sm_ty[tid] = -1;
        if (EDGE) { sm_s0[tid] = 0; sm_s1[tid] = 0; sm_dj[tid] = 0; }
      }
    }
    if (tid == 128) { sm_tmin = 1 << 30; sm_tmax = -1; }
    __syncthreads();
    if (tid < 128) {
      int ty = sm_ty[tid];
      if (ty >= 0) { atomicMin(&sm_tmin, ty); atomicMax(&sm_tmax, ty); }
    }
    __syncthreads();

    // per-lane A source pointers (2 rows x up-to-3 segments)
    const int ar0 = rb + l15, ar1 = ar0 + 16;
    const float *p0s0, *p0s1, *p0s2, *p1s0, *p1s1, *p1s2;
    if (EDGE) {
      p0s0 = feat + (size_t)sm_e[ar0] * 128;
      p0s1 = nf + (size_t)sm_s0[ar0] * 128;
      p0s2 = nf + (size_t)sm_s1[ar0] * 128;
      p1s0 = feat + (size_t)sm_e[ar1] * 128;
      p1s1 = nf + (size_t)sm_s0[ar1] * 128;
      p1s2 = nf + (size_t)sm_s1[ar1] * 128;
    } else {
      p0s0 = feat + (size_t)sm_e[ar0] * 128;
      p0s1 = nf + (size_t)sm_e[ar0] * 128;
      p0s2 = p0s1;
      p1s0 = feat + (size_t)sm_e[ar1] * 128;
      p1s1 = nf + (size_t)sm_e[ar1] * 128;
      p1s2 = p1s1;
    }

    const int tmin = sm_tmin, tmax = sm_tmax;
    for (int t = tmin; t <= tmax; ++t) {
      if (t != cur_t) {
        cur_t = t;
        __syncthreads();               // no wave may still read old Wsm
        {
          const uint4* g = (const uint4*)(pW1 + (size_t)t * (KB1 * 4096));
          uint4* d4 = (uint4*)Wsm;
#pragma unroll
          for (int q = 0; q < KB1; ++q) d4[q * 512 + tid] = g[q * 512 + tid];
        }
        {
          const bf16x8_t* g2 = (const bf16x8_t*)pW2;
#pragma unroll
          for (int kb = 0; kb < 4; ++kb)
#pragma unroll
            for (int n = 0; n < 4; ++n)
              w2r[kb * 4 + n] =
                  g2[(size_t)((t * 4 + kb) * 8 + (cb >> 4) + n) * 64 + l];
        }
#pragma unroll
        for (int n = 0; n < 4; ++n) {
          bh[n] = b1[t * 128 + cb + 16 * n + l15];
          bo[n] = b2[t * 128 + cb + 16 * n + l15];
        }
        __syncthreads();
      }

      // ---------------- layer 1: [128,K1] @ [K1,128] ----------------
      f32x4_t acc[2][4];
#pragma unroll
      for (int m = 0; m < 2; ++m)
#pragma unroll
        for (int n = 0; n < 4; ++n) acc[m][n] = (f32x4_t){0.f, 0.f, 0.f, 0.f};

      f32x4_t c0a, c0b, c1a, c1b, n0a, n0b, n1a, n1b;
      {
        const float* q0 = p0s0 + koff;
        const float* q1 = p1s0 + koff;
        c0a = ((const f32x4_t*)q0)[0]; c0b = ((const f32x4_t*)q0)[1];
        c1a = ((const f32x4_t*)q1)[0]; c1b = ((const f32x4_t*)q1)[1];
      }
#pragma unroll
      for (int kb = 0; kb < KB1; ++kb) {
        if (kb + 1 < KB1) {            // prefetch next k-step's A
          const float* pn0 = SELP(kb + 1, p0s0, p0s1, p0s2);
          const float* pn1 = SELP(kb + 1, p1s0, p1s1, p1s2);
          const float* q0 = pn0 + ((kb + 1) & 3) * 32 + koff;
          const float* q1 = pn1 + ((kb + 1) & 3) * 32 + koff;
          n0a = ((const f32x4_t*)q0)[0]; n0b = ((const f32x4_t*)q0)[1];
          n1a = ((const f32x4_t*)q1)[0]; n1b = ((const f32x4_t*)q1)[1];
        }
        bf16x8_t bfr[4];
#pragma unroll
        for (int n = 0; n < 4; ++n)
          bfr[n] = *(const bf16x8_t*)(Wsm + ((kb * 8 + (cb >> 4) + n) * 64 + l) * 16);
        bf16x8_t a0, a1;
        a0[0] = (bf16_t)c0a[0]; a0[1] = (bf16_t)c0a[1];
        a0[2] = (bf16_t)c0a[2]; a0[3] = (bf16_t)c0a[3];
        a0[4] = (bf16_t)c0b[0]; a0[5] = (bf16_t)c0b[1];
        a0[6] = (bf16_t)c0b[2]; a0[7] = (bf16_t)c0b[3];
        a1[0] = (bf16_t)c1a[0]; a1[1] = (bf16_t)c1a[1];
        a1[2] = (bf16_t)c1a[2]; a1[3] = (bf16_t)c1a[3];
        a1[4] = (bf16_t)c1b[0]; a1[5] = (bf16_t)c1b[1];
        a1[6] = (bf16_t)c1b[2]; a1[7] = (bf16_t)c1b[3];
#pragma unroll
        for (int n = 0; n < 4; ++n) {
          acc[0][n] = __builtin_amdgcn_mfma_f32_16x16x32_bf16(a0, bfr[n], acc[0][n], 0, 0, 0);
          acc[1][n] = __builtin_amdgcn_mfma_f32_16x16x32_bf16(a1, bfr[n], acc[1][n], 0, 0, 0);
        }
        c0a = n0a; c0b = n0b; c1a = n1a; c1b = n1b;
      }

      // bias + relu -> Hsm (bf16, swizzled). C/D: col=l&15, row=(l>>4)*4+jj.
#pragma unroll
      for (int n = 0; n < 4; ++n) {
        int col = cb + 16 * n + l15;
#pragma unroll
        for (int m = 0; m < 2; ++m)
#pragma unroll
          for (int jj = 0; jj < 4; ++jj) {
            int row = rb + 16 * m + ((l >> 4) << 2) + jj;
            float v = acc[m][n][jj] + bh[n];
            v = v > 0.f ? v : 0.f;
            *(bf16_t*)(Hsm + row * 256 + ((col * 2) ^ ((row & 7) << 4))) = (bf16_t)v;
          }
      }
      __syncthreads();                 // all H written before any layer-2 read

      // ---------------- layer 2: [128,128] @ [128,128] ----------------
      f32x4_t acc2[2][4];
#pragma unroll
      for (int m = 0; m < 2; ++m)
#pragma unroll
        for (int n = 0; n < 4; ++n) acc2[m][n] = (f32x4_t){0.f, 0.f, 0.f, 0.f};

#pragma unroll
      for (int kb = 0; kb < 4; ++kb) {
        const int kbyte = kb * 64 + ((l >> 4) << 4);
        const int row0 = rb + l15, row1 = row0 + 16;
        bf16x8_t h0 = *(const bf16x8_t*)(Hsm + row0 * 256 + (kbyte ^ ((row0 & 7) << 4)));
        bf16x8_t h1 = *(const bf16x8_t*)(Hsm + row1 * 256 + (kbyte ^ ((row1 & 7) << 4)));
#pragma unroll
        for (int n = 0; n < 4; ++n) {
          acc2[0][n] = __builtin_amdgcn_mfma_f32_16x16x32_bf16(h0, w2r[kb * 4 + n], acc2[0][n], 0, 0, 0);
          acc2[1][n] = __builtin_amdgcn_mfma_f32_16x16x32_bf16(h1, w2r[kb * 4 + n], acc2[1][n], 0, 0, 0);
        }
      }

      // ---------------- epilogue ----------------
#pragma unroll
      for (int n = 0; n < 4; ++n) {
        int col = cb + 16 * n + l15;
#pragma unroll
        for (int m = 0; m < 2; ++m)
#pragma unroll
          for (int jj = 0; jj < 4; ++jj) {
            int row = rb + 16 * m + ((l >> 4) << 2) + jj;
            int j = sm_j[row];
            if (j >= 0 && sm_ty[row] == t) {
              float v = acc2[m][n][jj] + bo[n];
              out[(size_t)j * 128 + col] = v;
              if (EDGE)
                unsafeAtomicAdd(agg_out + (size_t)sm_dj[row] * 128 + col, v);
            }
          }
      }
    }
  }
}

// ---------------------------------------------------------------------------
extern "C" void kernel_launch(void* const* d_in, const int* in_sizes, int n_in,
                              void* d_out, int out_size, void* d_ws, size_t ws_size,
                              hipStream_t stream)
{
  const float* nf    = (const float*)d_in[0];
  const float* ef    = (const float*)d_in[1];
  const int*   src   = (const int*)d_in[2];
  const int*   dst   = (const int*)d_in[3];
  const int*   etype = (const int*)d_in[4];
  const int*   ntype = (const int*)d_in[5];
  const float* Weh   = (const float*)d_in[6];
  const float* beh   = (const float*)d_in[7];
  const float* Weo   = (const float*)d_in[8];
  const float* beo   = (const float*)d_in[9];
  const float* Wnh   = (const float*)d_in[10];
  const float* bnh   = (const float*)d_in[11];
  const float* Wno   = (const float*)d_in[12];
  const float* bno   = (const float*)d_in[13];

  const int E = in_sizes[2];   // 800000
  const int N = in_sizes[5];   // 50000
  const int TE = 3, TN = 2;

  char* ws = (char*)d_ws;
  size_t off = 0;
  auto alloc = [&](size_t bytes) -> char* {
    char* p = ws + off;
    off = (off + bytes + 511) & ~(size_t)511;
    return p;
  };
  bf16_t* pWeh = (bf16_t*)alloc((size_t)TE * 12 * 8 * 512 * 2);
  bf16_t* pWeo = (bf16_t*)alloc((size_t)TE * 4 * 8 * 512 * 2);
  bf16_t* pWnh = (bf16_t*)alloc((size_t)TN * 8 * 8 * 512 * 2);
  bf16_t* pWno = (bf16_t*)alloc((size_t)TN * 4 * 8 * 512 * 2);
  int* rank_e = (int*)alloc((size_t)E * 4);
  int* perm_e = (int*)alloc((size_t)E * 4);
  int* rank_n = (int*)alloc((size_t)N * 4);
  int* perm_n = (int*)alloc((size_t)N * 4);
  const int NBE = (E + RCHUNK - 1) / RCHUNK;   // 196
  const int NBN = (N + RCHUNK - 1) / RCHUNK;   // 13
  int* blkcnt_e  = (int*)alloc((size_t)NBE * TE * 4);
  int* blkbase_e = (int*)alloc((size_t)NBE * TE * 4);
  int* blkcnt_n  = (int*)alloc((size_t)NBN * TN * 4);
  int* blkbase_n = (int*)alloc((size_t)NBN * TN * 4);
  float* agg = (float*)alloc((size_t)N * 128 * 4);
  (void)ws_size; (void)n_in; (void)out_size;

  hipMemsetAsync(agg, 0, (size_t)N * 128 * 4, stream);

  pack_w_kernel<<<288, 256, 0, stream>>>(Weh, pWeh, TE, 384, 128);
  pack_w_kernel<<<96, 256, 0, stream>>>(Weo, pWeo, TE, 128, 128);
  pack_w_kernel<<<128, 256, 0, stream>>>(Wnh, pWnh, TN, 256, 128);
  pack_w_kernel<<<64, 256, 0, stream>>>(Wno, pWno, TN, 128, 128);

  count_types_kernel<3><<<NBE, 256, 0, stream>>>(etype, E, blkcnt_e);
  scan_blocks_kernel<3><<<1, 256, 0, stream>>>(blkcnt_e, NBE, blkbase_e);
  write_ranks_kernel<3><<<NBE, 256, 0, stream>>>(etype, E, blkbase_e, rank_e, perm_e);

  count_types_kernel<2><<<NBN, 256, 0, stream>>>(ntype, N, blkcnt_n);
  scan_blocks_kernel<2><<<1, 256, 0, stream>>>(blkcnt_n, NBN, blkbase_n);
  write_ranks_kernel<2><<<NBN, 256, 0, stream>>>(ntype, N, blkbase_n, rank_n, perm_n);

  float* out_nf = (float*)d_out;                      // new_nf first
  float* out_ef = (float*)d_out + (size_t)N * 128;    // then new_ef

  mlp2_kernel<384, true><<<512, 512, 0, stream>>>(
      nf, ef, src, dst, etype, perm_e, rank_e,
      pWeh, beh, pWeo, beo, out_ef, agg, E);

  const int tiles_n = (N + 127) / 128;                // 391
  mlp2_kernel<256, false><<<tiles_n, 512, 0, stream>>>(
      nf, agg, nullptr, nullptr, ntype, perm_n, rank_n,
      pWnh, bnh, pWno, bno, out_nf, nullptr, N);
}

// Round 3
// 833.678 us; speedup vs baseline: 1.3025x; 1.1847x over previous
//
#include <hip/hip_runtime.h>

typedef __bf16 bf16_t;
typedef bf16_t bf16x8_t __attribute__((ext_vector_type(8)));
typedef float  f32x4_t  __attribute__((ext_vector_type(4)));

#define RCHUNK 4096

// ---------------------------------------------------------------------------
// Weight packing: W[t][k0+k][n] (f32, row-stride 128) -> bf16 MFMA-B-fragment
// order: out[((t*KB+kb)*8+nb)*512 + l*8 + j] = W[t][k0+kb*32+(l>>4)*8+j][nb*16+(l&15)]
// ---------------------------------------------------------------------------
__global__ void pack_w_kernel(const float* __restrict__ W, bf16_t* __restrict__ out,
                              int T, int Ksrc, int k0, int KB)
{
  int total = T * KB * 8 * 512;
  for (int idx = blockIdx.x * blockDim.x + threadIdx.x; idx < total;
       idx += gridDim.x * blockDim.x) {
    int j  = idx & 7;
    int l  = (idx >> 3) & 63;
    int nb = (idx >> 9) & 7;
    int r  = idx >> 12;
    int kb = r % KB;
    int t  = r / KB;
    int k = k0 + kb * 32 + ((l >> 4) << 3) + j;
    int n = nb * 16 + (l & 15);
    out[idx] = (bf16_t)W[((size_t)t * Ksrc + k) * 128 + n];
  }
}

// ---------------------------------------------------------------------------
// Stable counting-sort rank/perm over a small type alphabet T.
// ---------------------------------------------------------------------------
template <int T>
__global__ void count_types_kernel(const int* __restrict__ tv, int n,
                                   int* __restrict__ blkcnt)
{
  __shared__ int cnt[T];
  int tid = threadIdx.x, b = blockIdx.x;
  if (tid < T) cnt[tid] = 0;
  __syncthreads();
  int lo = b * RCHUNK, hi = min(n, lo + RCHUNK);
  int loc[T];
#pragma unroll
  for (int t = 0; t < T; ++t) loc[t] = 0;
  for (int i = lo + tid; i < hi; i += 256) {
    int tq = tv[i];
#pragma unroll
    for (int t = 0; t < T; ++t) loc[t] += (tq == t);
  }
#pragma unroll
  for (int t = 0; t < T; ++t)
    if (loc[t]) atomicAdd(&cnt[t], loc[t]);
  __syncthreads();
  if (tid < T) blkcnt[b * T + tid] = cnt[tid];
}

template <int T>
__global__ void scan_blocks_kernel(const int* __restrict__ blkcnt, int nblocks,
                                   int* __restrict__ blkbase)
{
  __shared__ int sh[256];
  __shared__ int tot[T];
  int tid = threadIdx.x;
  int myc[T], excl[T];
#pragma unroll
  for (int t = 0; t < T; ++t) myc[t] = (tid < nblocks) ? blkcnt[tid * T + t] : 0;
#pragma unroll
  for (int t = 0; t < T; ++t) {
    sh[tid] = myc[t];
    __syncthreads();
    for (int off = 1; off < 256; off <<= 1) {
      int v = (tid >= off) ? sh[tid - off] : 0;
      __syncthreads();
      sh[tid] += v;
      __syncthreads();
    }
    excl[t] = sh[tid] - myc[t];
    if (tid == 255) tot[t] = sh[255];
    __syncthreads();
  }
  if (tid < nblocks) {
    int run = 0;
#pragma unroll
    for (int t = 0; t < T; ++t) {
      blkbase[tid * T + t] = run + excl[t];
      run += tot[t];
    }
  }
}

template <int T>
__global__ void write_ranks_kernel(const int* __restrict__ tv, int n,
                                   const int* __restrict__ blkbase,
                                   int* __restrict__ rank, int* __restrict__ perm)
{
  __shared__ int sh[256];
  int tid = threadIdx.x, b = blockIdx.x;
  int lo = b * RCHUNK + tid * 16;
  int tvq[16];
  int myc[T];
#pragma unroll
  for (int t = 0; t < T; ++t) myc[t] = 0;
#pragma unroll
  for (int q = 0; q < 16; ++q) {
    int i = lo + q;
    int tq = (i < n) ? tv[i] : -1;
    tvq[q] = tq;
#pragma unroll
    for (int t = 0; t < T; ++t) myc[t] += (tq == t);
  }
  int mybase[T];
#pragma unroll
  for (int t = 0; t < T; ++t) {
    sh[tid] = myc[t];
    __syncthreads();
    for (int off = 1; off < 256; off <<= 1) {
      int v = (tid >= off) ? sh[tid - off] : 0;
      __syncthreads();
      sh[tid] += v;
      __syncthreads();
    }
    mybase[t] = blkbase[b * T + t] + sh[tid] - myc[t];
    __syncthreads();
  }
#pragma unroll
  for (int q = 0; q < 16; ++q) {
    int tq = tvq[q];
    if (tq < 0) continue;
    int r = 0;
#pragma unroll
    for (int t = 0; t < T; ++t)
      if (tq == t) { r = mybase[t]; mybase[t] = r + 1; }
    rank[lo + q] = r;
    perm[r] = lo + q;
  }
}

// ---------------------------------------------------------------------------
// P precompute: P[which] = nf @ Wk[which]  (bf16 out), 8 "which" slots:
// 0-2: Ps[t]=nf@W1s[t], 3-5: Pd[t]=nf@W1d[t], 6-7: Pn[t]=nf@Wn1b[t].
// Block 256 = 4 waves (2x2), tile 64 nodes, K=128, W in LDS.
// ---------------------------------------------------------------------------
__global__ __launch_bounds__(256) void precompute_p_kernel(
    const float* __restrict__ nf,
    const bf16_t* __restrict__ pW1s, const bf16_t* __restrict__ pW1d,
    const bf16_t* __restrict__ pWn1b,
    bf16_t* __restrict__ Ps, bf16_t* __restrict__ Pd, bf16_t* __restrict__ Pn,
    int Nn)
{
  __shared__ char Wsm[32768];
  const int which = blockIdx.x & 7, tile = blockIdx.x >> 3;
  const bf16_t* pB; bf16_t* po;
  if (which < 3)      { pB = pW1s + which * 16384;       po = Ps + (size_t)which * Nn * 128; }
  else if (which < 6) { pB = pW1d + (which - 3) * 16384; po = Pd + (size_t)(which - 3) * Nn * 128; }
  else                { pB = pWn1b + (which - 6) * 16384; po = Pn + (size_t)(which - 6) * Nn * 128; }

  const int tid = threadIdx.x, l = tid & 63, w = tid >> 6;
  const int rb = (w >> 1) * 32, cb = (w & 1) * 64, l15 = l & 15;
  const int koff = (l >> 4) << 3;

  {
    const uint4* g = (const uint4*)pB;
    uint4* d = (uint4*)Wsm;
#pragma unroll
    for (int q = 0; q < 8; ++q) d[q * 256 + tid] = g[q * 256 + tid];
  }

  const int base = tile * 64;
  const int r0 = base + rb + l15, r1 = r0 + 16;
  const float* q0 = nf + (size_t)min(r0, Nn - 1) * 128 + koff;
  const float* q1 = nf + (size_t)min(r1, Nn - 1) * 128 + koff;
  f32x4_t areg[2][4][2];
#pragma unroll
  for (int kb = 0; kb < 4; ++kb) {
    areg[0][kb][0] = ((const f32x4_t*)(q0 + kb * 32))[0];
    areg[0][kb][1] = ((const f32x4_t*)(q0 + kb * 32))[1];
    areg[1][kb][0] = ((const f32x4_t*)(q1 + kb * 32))[0];
    areg[1][kb][1] = ((const f32x4_t*)(q1 + kb * 32))[1];
  }
  __syncthreads();

  f32x4_t acc[2][4];
#pragma unroll
  for (int m = 0; m < 2; ++m)
#pragma unroll
    for (int n = 0; n < 4; ++n) acc[m][n] = (f32x4_t){0.f, 0.f, 0.f, 0.f};

#pragma unroll
  for (int kb = 0; kb < 4; ++kb) {
    bf16x8_t bfr[4];
#pragma unroll
    for (int n = 0; n < 4; ++n)
      bfr[n] = *(const bf16x8_t*)(Wsm + ((kb * 8 + (cb >> 4) + n) * 64 + l) * 16);
    bf16x8_t a0, a1;
#pragma unroll
    for (int z = 0; z < 4; ++z) {
      a0[z] = (bf16_t)areg[0][kb][0][z]; a0[4 + z] = (bf16_t)areg[0][kb][1][z];
      a1[z] = (bf16_t)areg[1][kb][0][z]; a1[4 + z] = (bf16_t)areg[1][kb][1][z];
    }
#pragma unroll
    for (int n = 0; n < 4; ++n) {
      acc[0][n] = __builtin_amdgcn_mfma_f32_16x16x32_bf16(a0, bfr[n], acc[0][n], 0, 0, 0);
      acc[1][n] = __builtin_amdgcn_mfma_f32_16x16x32_bf16(a1, bfr[n], acc[1][n], 0, 0, 0);
    }
  }

#pragma unroll
  for (int n = 0; n < 4; ++n) {
    int col = cb + 16 * n + l15;
#pragma unroll
    for (int m = 0; m < 2; ++m)
#pragma unroll
      for (int jj = 0; jj < 4; ++jj) {
        int row = rb + 16 * m + ((l >> 4) << 2) + jj;
        int node = base + row;
        if (node < Nn) po[(size_t)node * 128 + col] = (bf16_t)acc[m][n][jj];
      }
  }
}

// ---------------------------------------------------------------------------
// Fused per-type 2-layer MLP, K1=128 via P-precompute.
//   EDGE: h = relu(ef[e]@W1e[t] + Ps[t][src] + Pd[t][dst] + b1); out=h@W2+b2
//   NODE: h = relu(agg[n]@Wn1a[t] + Pn[t][n] + b1); out=h@W2+b2
// Block 256 = 4 waves (2x2 grid: wave = 32 rows x 64 cols), tile 64 rows,
// persistent over a contiguous (type-sorted) tile range.
// W1 in LDS (per type), W2 in registers, full-K A burst-prefetch in regs,
// Psum staged to LDS (bf16, chunk-XOR swizzle), H through swizzled LDS.
// ---------------------------------------------------------------------------
template <bool EDGE>
__global__ __launch_bounds__(256, 2) void mlp3_kernel(
    const float* __restrict__ feat,
    const int* __restrict__ src, const int* __restrict__ dst,
    const int* __restrict__ tvec,
    const int* __restrict__ perm, const int* __restrict__ rank,
    const bf16_t* __restrict__ pW1, const float* __restrict__ b1,
    const bf16_t* __restrict__ pW2, const float* __restrict__ b2,
    const bf16_t* __restrict__ P1, const bf16_t* __restrict__ P2, int pnodes,
    float* __restrict__ out, float* __restrict__ agg_out, int Ntot)
{
  __shared__ char Wsm[32768];          // W1[t], frag chunks (kb,nfr) of 1KB
  __shared__ char Psm[16384];          // Psum tile [64][128] bf16, chunk-swizzled
  __shared__ char Hsm[16384];          // hidden tile [64][128] bf16, XOR-swizzled
  __shared__ int sm_e[64], sm_j[64], sm_ty[64];
  __shared__ int sm_s0[64], sm_s1[64], sm_dj[64];
  __shared__ int sm_tmin, sm_tmax;

  const int tid = threadIdx.x;
  const int l = tid & 63, w = tid >> 6;
  const int rb = (w >> 1) * 32, cb = (w & 1) * 64;
  const int l15 = l & 15;
  const int koff = (l >> 4) << 3;

  const int tiles = (Ntot + 63) >> 6;
  const int tpb = (tiles + gridDim.x - 1) / gridDim.x;
  const int tb0 = blockIdx.x * tpb;
  const int tb1 = min(tiles, tb0 + tpb);

  int cur_t = -1;
  bf16x8_t w2r[16];
  float bh[4], bo[4];

  for (int tile = tb0; tile < tb1; ++tile) {
    const int base = tile << 6;
    __syncthreads();                   // B0: prev tile fully consumed
    if (tid < 64) {
      int pos = base + tid;
      int tyv = -1;
      if (pos < Ntot) {
        int e = perm[pos], j = rank[pos];
        sm_e[tid] = e; sm_j[tid] = j;
        tyv = tvec[e];
        if (EDGE) { sm_s0[tid] = src[e]; sm_s1[tid] = dst[e]; sm_dj[tid] = dst[j]; }
      } else {
        sm_e[tid] = 0; sm_j[tid] = -1;
        if (EDGE) { sm_s0[tid] = 0; sm_s1[tid] = 0; sm_dj[tid] = 0; }
      }
      sm_ty[tid] = tyv;
      int tmn = tyv < 0 ? 99 : tyv, tmx = tyv;
#pragma unroll
      for (int off = 32; off >= 1; off >>= 1) {
        tmn = min(tmn, __shfl_xor(tmn, off));
        tmx = max(tmx, __shfl_xor(tmx, off));
      }
      if (tid == 0) { sm_tmin = tmn; sm_tmax = tmx < 0 ? 0 : tmx; }
    }
    __syncthreads();                   // B1: meta visible

    // ---- burst A prefetch: lane's full-K slice of 2 rows ----
    const int ar0 = rb + l15, ar1 = ar0 + 16;
    const float* q0 = feat + (size_t)sm_e[ar0] * 128 + koff;
    const float* q1 = feat + (size_t)sm_e[ar1] * 128 + koff;
    f32x4_t areg[2][4][2];
#pragma unroll
    for (int kb = 0; kb < 4; ++kb) {
      areg[0][kb][0] = ((const f32x4_t*)(q0 + kb * 32))[0];
      areg[0][kb][1] = ((const f32x4_t*)(q0 + kb * 32))[1];
      areg[1][kb][0] = ((const f32x4_t*)(q1 + kb * 32))[0];
      areg[1][kb][1] = ((const f32x4_t*)(q1 + kb * 32))[1];
    }

    // ---- Psum gather -> Psm (bf16), chunk-swizzle c8^(row&15) ----
#pragma unroll
    for (int q = 0; q < 4; ++q) {
      int idx = tid * 4 + q;
      int row = idx >> 4, c8 = idx & 15;
      int ty = max(sm_ty[row], 0);
      bf16x8_t s;
      if (EDGE) {
        bf16x8_t u = ((const bf16x8_t*)(P1 + ((size_t)ty * pnodes + sm_s0[row]) * 128))[c8];
        bf16x8_t v = ((const bf16x8_t*)(P2 + ((size_t)ty * pnodes + sm_s1[row]) * 128))[c8];
#pragma unroll
        for (int z = 0; z < 8; ++z) s[z] = (bf16_t)((float)u[z] + (float)v[z]);
      } else {
        s = ((const bf16x8_t*)(P1 + ((size_t)ty * pnodes + sm_e[row]) * 128))[c8];
      }
      *(bf16x8_t*)(Psm + row * 256 + ((c8 ^ (row & 15)) << 4)) = s;
    }

    const int tmin = sm_tmin, tmax = sm_tmax;
    for (int t = tmin; t <= tmax; ++t) {
      if (t != cur_t) {
        __syncthreads();               // no wave still reading old Wsm
        {
          const uint4* g = (const uint4*)(pW1 + (size_t)t * 16384);
          uint4* d = (uint4*)Wsm;
#pragma unroll
          for (int q = 0; q < 8; ++q) d[q * 256 + tid] = g[q * 256 + tid];
        }
        {
          const bf16x8_t* g2 = (const bf16x8_t*)pW2;
#pragma unroll
          for (int kb = 0; kb < 4; ++kb)
#pragma unroll
            for (int n = 0; n < 4; ++n)
              w2r[kb * 4 + n] = g2[(size_t)((t * 4 + kb) * 8 + (cb >> 4) + n) * 64 + l];
        }
#pragma unroll
        for (int n = 0; n < 4; ++n) {
          bh[n] = b1[t * 128 + cb + 16 * n + l15];
          bo[n] = b2[t * 128 + cb + 16 * n + l15];
        }
        cur_t = t;
        __syncthreads();
      }

      // ---------------- layer 1 ----------------
      f32x4_t acc[2][4];
#pragma unroll
      for (int m = 0; m < 2; ++m)
#pragma unroll
        for (int n = 0; n < 4; ++n) acc[m][n] = (f32x4_t){0.f, 0.f, 0.f, 0.f};

#pragma unroll
      for (int kb = 0; kb < 4; ++kb) {
        bf16x8_t bfr[4];
#pragma unroll
        for (int n = 0; n < 4; ++n)
          bfr[n] = *(const bf16x8_t*)(Wsm + ((kb * 8 + (cb >> 4) + n) * 64 + l) * 16);
        bf16x8_t a0, a1;
#pragma unroll
        for (int z = 0; z < 4; ++z) {
          a0[z] = (bf16_t)areg[0][kb][0][z]; a0[4 + z] = (bf16_t)areg[0][kb][1][z];
          a1[z] = (bf16_t)areg[1][kb][0][z]; a1[4 + z] = (bf16_t)areg[1][kb][1][z];
        }
#pragma unroll
        for (int n = 0; n < 4; ++n) {
          acc[0][n] = __builtin_amdgcn_mfma_f32_16x16x32_bf16(a0, bfr[n], acc[0][n], 0, 0, 0);
          acc[1][n] = __builtin_amdgcn_mfma_f32_16x16x32_bf16(a1, bfr[n], acc[1][n], 0, 0, 0);
        }
      }

      __syncthreads();                 // B3: Psm ready; prev-t Hsm reads done
      // h = relu(acc + Psum + b1) -> Hsm
#pragma unroll
      for (int n = 0; n < 4; ++n) {
        int col = cb + 16 * n + l15;
        int byte = col * 2;
#pragma unroll
        for (int m = 0; m < 2; ++m)
#pragma unroll
          for (int jj = 0; jj < 4; ++jj) {
            int row = rb + 16 * m + ((l >> 4) << 2) + jj;
            float pv = (float)*(const bf16_t*)(
                Psm + row * 256 + ((byte & 15) | ((((byte >> 4) ^ (row & 15)) & 15) << 4)));
            float v = acc[m][n][jj] + pv + bh[n];
            v = v > 0.f ? v : 0.f;
            *(bf16_t*)(Hsm + row * 256 + (byte ^ ((row & 7) << 4))) = (bf16_t)v;
          }
      }
      __syncthreads();                 // B4: Hsm visible

      // ---------------- layer 2 ----------------
      f32x4_t acc2[2][4];
#pragma unroll
      for (int m = 0; m < 2; ++m)
#pragma unroll
        for (int n = 0; n < 4; ++n) acc2[m][n] = (f32x4_t){0.f, 0.f, 0.f, 0.f};

#pragma unroll
      for (int kb = 0; kb < 4; ++kb) {
        int kbyte = kb * 64 + ((l >> 4) << 4);
        int row0 = rb + l15, row1 = row0 + 16;
        bf16x8_t h0 = *(const bf16x8_t*)(Hsm + row0 * 256 + (kbyte ^ ((row0 & 7) << 4)));
        bf16x8_t h1 = *(const bf16x8_t*)(Hsm + row1 * 256 + (kbyte ^ ((row1 & 7) << 4)));
#pragma unroll
        for (int n = 0; n < 4; ++n) {
          acc2[0][n] = __builtin_amdgcn_mfma_f32_16x16x32_bf16(h0, w2r[kb * 4 + n], acc2[0][n], 0, 0, 0);
          acc2[1][n] = __builtin_amdgcn_mfma_f32_16x16x32_bf16(h1, w2r[kb * 4 + n], acc2[1][n], 0, 0, 0);
        }
      }

      // ---------------- epilogue ----------------
#pragma unroll
      for (int n = 0; n < 4; ++n) {
        int col = cb + 16 * n + l15;
#pragma unroll
        for (int m = 0; m < 2; ++m)
#pragma unroll
          for (int jj = 0; jj < 4; ++jj) {
            int row = rb + 16 * m + ((l >> 4) << 2) + jj;
            int j = sm_j[row];
            if (j >= 0 && sm_ty[row] == t) {
              float v = acc2[m][n][jj] + bo[n];
              out[(size_t)j * 128 + col] = v;
              if (EDGE)
                unsafeAtomicAdd(agg_out + (size_t)sm_dj[row] * 128 + col, v);
            }
          }
      }
    }
  }
}

// ---------------------------------------------------------------------------
extern "C" void kernel_launch(void* const* d_in, const int* in_sizes, int n_in,
                              void* d_out, int out_size, void* d_ws, size_t ws_size,
                              hipStream_t stream)
{
  const float* nf    = (const float*)d_in[0];
  const float* ef    = (const float*)d_in[1];
  const int*   src   = (const int*)d_in[2];
  const int*   dst   = (const int*)d_in[3];
  const int*   etype = (const int*)d_in[4];
  const int*   ntype = (const int*)d_in[5];
  const float* Weh   = (const float*)d_in[6];
  const float* beh   = (const float*)d_in[7];
  const float* Weo   = (const float*)d_in[8];
  const float* beo   = (const float*)d_in[9];
  const float* Wnh   = (const float*)d_in[10];
  const float* bnh   = (const float*)d_in[11];
  const float* Wno   = (const float*)d_in[12];
  const float* bno   = (const float*)d_in[13];

  const int E = in_sizes[2];   // 800000
  const int N = in_sizes[5];   // 50000
  const int TE = 3, TN = 2;

  char* ws = (char*)d_ws;
  size_t off = 0;
  auto alloc = [&](size_t bytes) -> char* {
    char* p = ws + off;
    off = (off + bytes + 511) & ~(size_t)511;
    return p;
  };
  // packed weights (frag order, bf16; 16384 elems = 32KB per type-matrix)
  bf16_t* pW1e  = (bf16_t*)alloc((size_t)TE * 16384 * 2);
  bf16_t* pW1s  = (bf16_t*)alloc((size_t)TE * 16384 * 2);
  bf16_t* pW1d  = (bf16_t*)alloc((size_t)TE * 16384 * 2);
  bf16_t* pWe2  = (bf16_t*)alloc((size_t)TE * 16384 * 2);
  bf16_t* pWn1a = (bf16_t*)alloc((size_t)TN * 16384 * 2);
  bf16_t* pWn1b = (bf16_t*)alloc((size_t)TN * 16384 * 2);
  bf16_t* pWn2  = (bf16_t*)alloc((size_t)TN * 16384 * 2);
  // P projections (bf16)
  bf16_t* Ps = (bf16_t*)alloc((size_t)TE * N * 128 * 2);
  bf16_t* Pd = (bf16_t*)alloc((size_t)TE * N * 128 * 2);
  bf16_t* Pn = (bf16_t*)alloc((size_t)TN * N * 128 * 2);
  // sort scratch
  int* rank_e = (int*)alloc((size_t)E * 4);
  int* perm_e = (int*)alloc((size_t)E * 4);
  int* rank_n = (int*)alloc((size_t)N * 4);
  int* perm_n = (int*)alloc((size_t)N * 4);
  const int NBE = (E + RCHUNK - 1) / RCHUNK;   // 196
  const int NBN = (N + RCHUNK - 1) / RCHUNK;   // 13
  int* blkcnt_e  = (int*)alloc((size_t)NBE * TE * 4);
  int* blkbase_e = (int*)alloc((size_t)NBE * TE * 4);
  int* blkcnt_n  = (int*)alloc((size_t)NBN * TN * 4);
  int* blkbase_n = (int*)alloc((size_t)NBN * TN * 4);
  float* agg = (float*)alloc((size_t)N * 128 * 4);
  (void)ws_size; (void)n_in; (void)out_size;

  hipMemsetAsync(agg, 0, (size_t)N * 128 * 4, stream);

  // pack: We_h rows [0:128)=W1e, [128:256)=W1s, [256:384)=W1d; Wn_h [0:128)=Wn1a, [128:256)=Wn1b
  pack_w_kernel<<<192, 256, 0, stream>>>(Weh, pW1e, TE, 384, 0, 4);
  pack_w_kernel<<<192, 256, 0, stream>>>(Weh, pW1s, TE, 384, 128, 4);
  pack_w_kernel<<<192, 256, 0, stream>>>(Weh, pW1d, TE, 384, 256, 4);
  pack_w_kernel<<<192, 256, 0, stream>>>(Weo, pWe2, TE, 128, 0, 4);
  pack_w_kernel<<<128, 256, 0, stream>>>(Wnh, pWn1a, TN, 256, 0, 4);
  pack_w_kernel<<<128, 256, 0, stream>>>(Wnh, pWn1b, TN, 256, 128, 4);
  pack_w_kernel<<<128, 256, 0, stream>>>(Wno, pWn2, TN, 128, 0, 4);

  const int ptiles = (N + 63) / 64;            // 782
  precompute_p_kernel<<<ptiles * 8, 256, 0, stream>>>(
      nf, pW1s, pW1d, pWn1b, Ps, Pd, Pn, N);

  count_types_kernel<3><<<NBE, 256, 0, stream>>>(etype, E, blkcnt_e);
  scan_blocks_kernel<3><<<1, 256, 0, stream>>>(blkcnt_e, NBE, blkbase_e);
  write_ranks_kernel<3><<<NBE, 256, 0, stream>>>(etype, E, blkbase_e, rank_e, perm_e);

  count_types_kernel<2><<<NBN, 256, 0, stream>>>(ntype, N, blkcnt_n);
  scan_blocks_kernel<2><<<1, 256, 0, stream>>>(blkcnt_n, NBN, blkbase_n);
  write_ranks_kernel<2><<<NBN, 256, 0, stream>>>(ntype, N, blkbase_n, rank_n, perm_n);

  float* out_nf = (float*)d_out;                      // new_nf first
  float* out_ef = (float*)d_out + (size_t)N * 128;    // then new_ef

  mlp3_kernel<true><<<512, 256, 0, stream>>>(
      ef, src, dst, etype, perm_e, rank_e,
      pW1e, beh, pWe2, beo, Ps, Pd, N, out_ef, agg, E);

  mlp3_kernel<false><<<512, 256, 0, stream>>>(
      agg, nullptr, nullptr, ntype, perm_n, rank_n,
      pWn1a, bnh, pWn2, bno, Pn, nullptr, N, out_nf, nullptr, N);
}